// Round 2
// 579.762 us; speedup vs baseline: 1.0072x; 1.0072x over previous
//
#include <hip/hip_runtime.h>
#include <hip/hip_bf16.h>
#include <stdint.h>

// Problem: B=32, T=2048, D=1024, U=1024, all fp32 in/out.
// out = [context 32*1024, attention_weights 32*2048]
//
// ws layout (big mode, needs WS_NEED bytes):
//   [0, 2MB)            W1f bf16 — W1 packed in MFMA B-fragment order
//   [2MB, +128KB)       qp2 fp32 [B][U] = query@W2 + b2 + b1
//   [+128KB, +256KB)    escore fp32 [B][T] = exp(score) (unnormalized)
//   [+256KB, +4MB)      pctx fp32 [1024 blocks][1024] partial contexts
//   [+4MB, +4KB)        pden fp32 [1024] partial softmax denominators
//
// small-ws fallback (fits the previously-verified 2.49MB footprint):
//   escore -> out attw region (in-place normalize later)
//   pctx   -> atomicAdd directly into out ctx (zeroed by k_prep)
//   pden   -> 32 floats at WS_ESC (atomicAdd, zeroed by k_prep)
#define WS_W1F   0
#define WS_QP2   2097152
#define WS_ESC   (WS_QP2 + 131072)
#define WS_PCTX  (WS_ESC + 262144)
#define WS_PDEN  (WS_PCTX + 4194304)
#define WS_NEED  (WS_PDEN + 4096)

typedef __attribute__((ext_vector_type(8))) short bf16x8;
typedef __attribute__((ext_vector_type(4))) float f32x4;

__device__ inline uint16_t f2b(float f) {
    __hip_bfloat16 h = __float2bfloat16(f);
    return *reinterpret_cast<uint16_t*>(&h);
}

// ---------------- Kernel 1: prep = W1 repack + qp2 (+ optional zeroing) -----
// blocks 0..255: repack 8 fragments each (2048 fragments of 1KB total)
// blocks 256..383: qp2 on (b, u-quarter): 128 blocks, each reads 1MB of W2.
//   In small-ws mode the qc==0 block of each b also zeroes out-ctx[b] (+pden).
__global__ __launch_bounds__(256) void k_prep(const float* __restrict__ W1,
                                              const float* __restrict__ query,
                                              const float* __restrict__ W2,
                                              const float* __restrict__ b1,
                                              const float* __restrict__ b2,
                                              __hip_bfloat16* __restrict__ W1f,
                                              float* __restrict__ qp2,
                                              float* __restrict__ zctx,
                                              float* __restrict__ zden) {
    __shared__ float qs[1024];
    int blk = blockIdx.x, tid = threadIdx.x;
    if (blk < 256) {
        int lane = tid & 63, fi = tid >> 6;
        int l15 = lane & 15, quad = lane >> 4;
        #pragma unroll
        for (int p = 0; p < 2; ++p) {
            int frag = blk * 8 + p * 4 + fi;      // 0..2047
            int ut = frag >> 5, ks = frag & 31;
            union { uint16_t h[8]; int4 v; } pk;
            #pragma unroll
            for (int j = 0; j < 8; ++j) {
                float x = W1[(size_t)(ks * 32 + quad * 8 + j) * 1024 + ut * 16 + l15];
                pk.h[j] = f2b(x);
            }
            *(int4*)((char*)W1f + (size_t)frag * 1024 + lane * 16) = pk.v;
        }
    } else {
        int bq = blk - 256;            // 0..127
        int b = bq >> 2, qc = bq & 3;
        if (zctx != nullptr && qc == 0) {
            *(float4*)(zctx + b * 1024 + tid * 4) = make_float4(0.f, 0.f, 0.f, 0.f);
            if (b == 0 && tid < 32) zden[tid] = 0.f;
        }
        int u = qc * 256 + tid;
        const float* q = query + b * 1024;
        #pragma unroll
        for (int i = 0; i < 4; ++i) qs[i * 256 + tid] = q[i * 256 + tid];
        __syncthreads();
        float a = b1[u] + b2[u];
        #pragma unroll 8
        for (int d = 0; d < 1024; ++d)
            a += qs[d] * W2[(size_t)d * 1024 + u];
        qp2[b * 1024 + u] = a;
    }
}

// ---------------- Kernel 2: fused score+exp+partial-context ----------
// Grid 1024 = 32 b * 32 row-tiles of 64. Block 512 (8 waves, 2/SIMD).
// A resident in LDS (64 rows x 1024 k bf16, XOR-swizzled 16B chunks, 0 conflicts).
// B from global in fragment-packed order (coalesced 1KB segments, L2-resident).
// Wave w owns u-stripe [w*128, +128): rt=4 (64 rows), ct=8.
// Epilogue: s -> e = exp(s) (no max-sub needed: |s| <= sum|V| ~ 16, sigma~0.4),
// then partial context sum_t e_t * values[t,:] from the (L2/L3-hot) tile rows.
__global__ __launch_bounds__(512, 1) void k_score(
        const float* __restrict__ values, const __hip_bfloat16* __restrict__ W1f,
        const float* __restrict__ qp2, const float* __restrict__ V,
        float* __restrict__ escore, float* __restrict__ pctx,
        float* __restrict__ pden, float* __restrict__ ctxa) {
    extern __shared__ char smem[];
    uint16_t* Al = (uint16_t*)smem;             // 64 x 1024 bf16 (swizzled)
    float* red = (float*)(smem + 131072);       // [8 stripes][64 rows]

    const int tid = threadIdx.x;
    const int lane = tid & 63, w = tid >> 6;
    const int quad = lane >> 4, l15 = lane & 15;
    const int b = blockIdx.x >> 5, trow0 = (blockIdx.x & 31) << 6;

    // ---- stage A: values[b, trow0..+64, :] fp32 -> bf16 LDS (once) ----
    const float* Ag = values + (size_t)(b * 2048 + trow0) * 1024;
    #pragma unroll
    for (int i = 0; i < 16; ++i) {
        int id = i * 512 + tid;
        int row = id >> 7, c = id & 127;
        const float* src = Ag + (size_t)row * 1024 + c * 8;
        float4 v0 = *(const float4*)src;
        float4 v1 = *(const float4*)(src + 4);
        union { uint16_t h[8]; int4 v; } pk;
        pk.h[0]=f2b(v0.x); pk.h[1]=f2b(v0.y); pk.h[2]=f2b(v0.z); pk.h[3]=f2b(v0.w);
        pk.h[4]=f2b(v1.x); pk.h[5]=f2b(v1.y); pk.h[6]=f2b(v1.z); pk.h[7]=f2b(v1.w);
        int pos = (c & 112) | ((c & 15) ^ (row & 15));
        *(int4*)(Al + (size_t)row * 1024 + pos * 8) = pk.v;
    }
    __syncthreads();

    // per-lane fragment base: frag(ut = w*8 + ct, ks) at byte (ut*32+ks)*1024
    const char* Bbase = (const char*)W1f + (size_t)(w * 8) * 32768 + lane * 16;

    f32x4 acc[4][8];
    #pragma unroll
    for (int rt = 0; rt < 4; ++rt)
        #pragma unroll
        for (int ct = 0; ct < 8; ++ct) acc[rt][ct] = (f32x4){0.f, 0.f, 0.f, 0.f};

    bf16x8 af[2][4], bfr[2][8];
    {   // prologue: ks = 0
        int pos = (quad & 15) ^ l15;   // cb = quad
        #pragma unroll
        for (int rt = 0; rt < 4; ++rt)
            af[0][rt] = *(bf16x8*)(Al + (rt * 16 + l15) * 1024 + pos * 8);
        #pragma unroll
        for (int ct = 0; ct < 8; ++ct)
            bfr[0][ct] = *(const bf16x8*)(Bbase + (size_t)(ct * 32) * 1024);
    }

    #pragma unroll 2
    for (int ks = 0; ks < 32; ++ks) {
        int cur = ks & 1, nxt = cur ^ 1;
        if (ks < 31) {
            int cb = (ks + 1) * 4 + quad;
            int pos = (cb & 112) | ((cb & 15) ^ l15);
            #pragma unroll
            for (int rt = 0; rt < 4; ++rt)
                af[nxt][rt] = *(bf16x8*)(Al + (rt * 16 + l15) * 1024 + pos * 8);
            #pragma unroll
            for (int ct = 0; ct < 8; ++ct)
                bfr[nxt][ct] = *(const bf16x8*)(Bbase + (size_t)(ct * 32 + ks + 1) * 1024);
        }
        #pragma unroll
        for (int rt = 0; rt < 4; ++rt)
            #pragma unroll
            for (int ct = 0; ct < 8; ++ct)
                acc[rt][ct] = __builtin_amdgcn_mfma_f32_16x16x32_bf16(
                    af[cur][rt], bfr[cur][ct], acc[rt][ct], 0, 0, 0);
    }

    // ---- epilogue: tanh(acc + qp2[u]) * V[u], per-lane row partials ----
    float srow[4][4];
    #pragma unroll
    for (int rt = 0; rt < 4; ++rt)
        #pragma unroll
        for (int r = 0; r < 4; ++r) srow[rt][r] = 0.f;
    #pragma unroll
    for (int ct = 0; ct < 8; ++ct) {
        int u = w * 128 + ct * 16 + l15;
        float qv = qp2[b * 1024 + u];
        float vv = V[u];
        #pragma unroll
        for (int rt = 0; rt < 4; ++rt)
            #pragma unroll
            for (int r = 0; r < 4; ++r) {
                float x = acc[rt][ct][r] + qv;
                float e = __expf(2.f * x);
                float t = 1.f - 2.f * __builtin_amdgcn_rcpf(1.f + e);
                srow[rt][r] += t * vv;
            }
    }

    // reduce u: over 16 lanes (l15), then over the 8 wave-stripes via LDS
    #pragma unroll
    for (int rt = 0; rt < 4; ++rt)
        #pragma unroll
        for (int r = 0; r < 4; ++r) {
            float s = srow[rt][r];
            s += __shfl_xor(s, 1, 64);
            s += __shfl_xor(s, 2, 64);
            s += __shfl_xor(s, 4, 64);
            s += __shfl_xor(s, 8, 64);
            srow[rt][r] = s;
        }
    if (l15 == 0) {
        #pragma unroll
        for (int rt = 0; rt < 4; ++rt)
            #pragma unroll
            for (int r = 0; r < 4; ++r)
                red[w * 64 + rt * 16 + quad * 4 + r] = srow[rt][r];
    }
    __syncthreads();

    // ---- fused: e = exp(score); partial denom; partial context ----
    float* wl = (float*)smem;    // alias A region (done with it, post-barrier)
    if (tid < 64) {
        float s = 0.f;
        #pragma unroll
        for (int k = 0; k < 8; ++k) s += red[k * 64 + tid];
        float e = __expf(s);
        escore[b * 2048 + trow0 + tid] = e;
        wl[tid] = e;
        float dsum = e;
        #pragma unroll
        for (int off = 32; off; off >>= 1) dsum += __shfl_xor(dsum, off, 64);
        if (tid == 0) {
            if (pctx != nullptr) pden[blockIdx.x] = dsum;
            else                 atomicAdd(&pden[b], dsum);
        }
    }
    __syncthreads();

    // weighted sum over this tile's 64 rows; thread owns a float2 of columns.
    // Rows were staged from global at kernel start -> L2/L3-hot re-read.
    {
        const float* Vg = values + (size_t)(b * 2048 + trow0) * 1024 + tid * 2;
        float ax = 0.f, ay = 0.f;
        #pragma unroll 8
        for (int t = 0; t < 64; ++t) {
            float wv = wl[t];
            float2 v = *(const float2*)(Vg + (size_t)t * 1024);
            ax += wv * v.x; ay += wv * v.y;
        }
        if (pctx != nullptr) {
            *(float2*)(pctx + (size_t)blockIdx.x * 1024 + tid * 2) = make_float2(ax, ay);
        } else {
            float* o = ctxa + b * 1024 + tid * 2;
            atomicAdd(o + 0, ax);
            atomicAdd(o + 1, ay);
        }
    }
}

// ---------------- Kernel 3: reduce partials, normalize ctx + attw ----
// Grid 32 (one per b), 256 threads. Big mode: reads 32 partial contexts
// (128KB) + escore per block, all L2-hot, no atomics. Small mode: scales the
// atomically-accumulated ctx and attw in place.
__global__ __launch_bounds__(256) void k_final(const float* __restrict__ pctx,
                                               const float* __restrict__ pden,
                                               const float* __restrict__ escore,
                                               float* __restrict__ out) {
    __shared__ float sinv;
    int b = blockIdx.x, tid = threadIdx.x;
    if (tid == 0) {
        float dsum = 0.f;
        if (pctx != nullptr) {
            #pragma unroll
            for (int t = 0; t < 32; ++t) dsum += pden[b * 32 + t];
        } else {
            dsum = pden[b];
        }
        sinv = 1.f / dsum;
    }
    __syncthreads();
    float inv = sinv;

    int d = tid * 4;
    if (pctx != nullptr) {
        float4 a = {0.f, 0.f, 0.f, 0.f};
        #pragma unroll 8
        for (int t = 0; t < 32; ++t) {
            float4 p = *(const float4*)(pctx + (size_t)(b * 32 + t) * 1024 + d);
            a.x += p.x; a.y += p.y; a.z += p.z; a.w += p.w;
        }
        a.x *= inv; a.y *= inv; a.z *= inv; a.w *= inv;
        *(float4*)(out + b * 1024 + d) = a;
    } else {
        float4 a = *(const float4*)(out + b * 1024 + d);
        a.x *= inv; a.y *= inv; a.z *= inv; a.w *= inv;
        *(float4*)(out + b * 1024 + d) = a;
    }

    // attention weights: e / denom (in small mode escore == out+32768: in-place)
    #pragma unroll
    for (int i = 0; i < 8; ++i) {
        int t = i * 256 + tid;
        out[32768 + b * 2048 + t] = escore[b * 2048 + t] * inv;
    }
}

extern "C" void kernel_launch(void* const* d_in, const int* in_sizes, int n_in,
                              void* d_out, int out_size, void* d_ws, size_t ws_size,
                              hipStream_t stream) {
    const float* query  = (const float*)d_in[0];
    const float* values = (const float*)d_in[1];
    const float* W1 = (const float*)d_in[2];
    const float* b1 = (const float*)d_in[3];
    const float* W2 = (const float*)d_in[4];
    const float* b2 = (const float*)d_in[5];
    const float* V  = (const float*)d_in[6];
    // d_in[7] = bv: adds a constant pre-softmax -> cancels in softmax; unused.

    char* ws = (char*)d_ws;
    __hip_bfloat16* W1f = (__hip_bfloat16*)(ws + WS_W1F);
    float* qp2 = (float*)(ws + WS_QP2);
    float* out = (float*)d_out;

    const bool big = ws_size >= (size_t)WS_NEED;
    float* escore = big ? (float*)(ws + WS_ESC)  : out + 32768;
    float* pctx   = big ? (float*)(ws + WS_PCTX) : nullptr;
    float* pden   = big ? (float*)(ws + WS_PDEN) : (float*)(ws + WS_ESC);
    float* zctx   = big ? nullptr : out;
    float* zden   = big ? nullptr : pden;

    (void)hipFuncSetAttribute((const void*)k_score,
                              hipFuncAttributeMaxDynamicSharedMemorySize, 133120);

    k_prep<<<384, 256, 0, stream>>>(W1, query, W2, b1, b2, W1f, qp2, zctx, zden);
    k_score<<<1024, 512, 133120, stream>>>(values, W1f, qp2, V, escore, pctx, pden, out);
    k_final<<<32, 256, 0, stream>>>(pctx, pden, escore, out);
}